// Round 4
// baseline (186.806 us; speedup 1.0000x reference)
//
#include <hip/hip_runtime.h>
#include <math.h>

// OHNM loss: pos BCE sum + top-k(600000) negative softplus sum, mean over 800000.
//
// R4 structure: ONE full pass (k_main) reads x,y (67 MB), accumulates the
// positive BCE sum and compacts all negative keys >= K0 (x >= 1.0, monotone
// uint32 key) -- expected ~1.3M candidates vs k=600K (2.2x margin for N(0,1)).
// Exact 12/10/10-bit radix-select then runs entirely on the 5.2 MB candidate
// array. Each stage kernel re-derives the previous stage's scan in-block
// (deterministic) so there are no separate scan dispatches. Level-3 bins fully
// determine the key, so ties are handled exactly by counts (matches top_k
// semantics: tied values contribute identical softplus).
// Fallback (cand_count < k): stage kernels additionally stream below-K0 keys
// from x,y -- exact for ANY input, never triggered for N(0,1) at this k/n.

#define NBINS1 4096
#define NBINS2 1024
#define LBUF_CAP 4096
#define K0 0xBF800000u      // f2key(1.0f)
#define CTRL_BYTES 32768

struct Ctrl {
    unsigned hist1[NBINS1];   // top-12 bits of candidate keys
    unsigned hist2[NBINS2];   // mid-10 bits, top12 == b1
    unsigned hist3[NBINS2];   // low-10 bits, top22 == (b1,b2)
    float    pos_sum;
    float    neg_sum;
    unsigned cand_count;
    unsigned Kneg;            // 3 * pos_num
    unsigned done;            // k_sum completion ticket
    unsigned b1, r1, b2, r2;  // stage results (written by h2/h3)
};

__device__ __forceinline__ unsigned f2key(float x) {
    unsigned u = __float_as_uint(x);
    return (u & 0x80000000u) ? ~u : (u | 0x80000000u);
}
__device__ __forceinline__ float key2f(unsigned k) {
    unsigned u = (k & 0x80000000u) ? (k & 0x7FFFFFFFu) : ~k;
    return __uint_as_float(u);
}
__device__ __forceinline__ float softplusf(float x) {
    return fmaxf(x, 0.0f) + __logf(1.0f + __expf(-fabsf(x)));
}
__device__ __forceinline__ float wred(float v) {
    v += __shfl_down(v, 32); v += __shfl_down(v, 16); v += __shfl_down(v, 8);
    v += __shfl_down(v, 4);  v += __shfl_down(v, 2);  v += __shfl_down(v, 1);
    return v;
}

// descending rank-select over a histogram, computed redundantly per block.
// Returns first bin (from the top) where cumulative >= R, and remaining rank
// r = R - count_strictly_above (>= 1). 256 threads, nbins in {1024, 4096}.
__device__ void scan_desc(const unsigned* __restrict__ hist, int nbins, unsigned R,
                          unsigned* bin_out, unsigned* r_out) {
    __shared__ unsigned sums[256];
    __shared__ unsigned res[2];
    const int per = nbins / 256;
    const int t = threadIdx.x;
    unsigned local[16];
    unsigned s = 0;
    for (int j = 0; j < per; ++j) {
        local[j] = hist[nbins - 1 - (t * per + j)];
        s += local[j];
    }
    if (t == 0) { res[0] = 0u; res[1] = 1u; }
    sums[t] = s;
    __syncthreads();
    for (int off = 1; off < 256; off <<= 1) {
        unsigned v = (t >= off) ? sums[t - off] : 0u;
        __syncthreads();
        sums[t] += v;
        __syncthreads();
    }
    const unsigned incl = sums[t];
    const unsigned excl = incl - s;
    if (excl < R && incl >= R) {
        unsigned cum = excl;
        for (int j = 0; j < per; ++j) {
            if (cum + local[j] >= R) {
                res[0] = (unsigned)(nbins - 1 - (t * per + j));
                res[1] = R - cum;
                break;
            }
            cum += local[j];
        }
    }
    __syncthreads();
    *bin_out = res[0];
    *r_out = res[1];
    __syncthreads();
}

// ---------------- init: zero control region, stash Kneg ----------------
__global__ void k_init(unsigned* ws, const int* __restrict__ pos_num) {
    const int stride = gridDim.x * blockDim.x;
    for (int i = blockIdx.x * blockDim.x + threadIdx.x; i < CTRL_BYTES / 4; i += stride)
        ws[i] = 0u;
    if (blockIdx.x == 0 && threadIdx.x == 0) {
        Ctrl* c = (Ctrl*)ws;
        c->Kneg = (unsigned)(pos_num[0] * 3);
    }
}

// ------- the ONE full pass: pos BCE sum + compact negative keys >= K0 -------
__global__ __launch_bounds__(256)
void k_main(const float* __restrict__ x, const float* __restrict__ y,
            Ctrl* __restrict__ ctrl, unsigned* __restrict__ cand,
            unsigned cap, int n) {
    __shared__ unsigned lbuf[LBUF_CAP];
    __shared__ unsigned lcount, gbase;
    __shared__ float red;
    if (threadIdx.x == 0) { lcount = 0u; red = 0.0f; }
    __syncthreads();
    float ps = 0.0f;
    const int n4 = n >> 2;
    const float4* x4 = (const float4*)x;
    const float4* y4 = (const float4*)y;
    const int stride = gridDim.x * blockDim.x;
    for (int i = blockIdx.x * blockDim.x + threadIdx.x; i < n4; i += stride) {
        float4 xv = x4[i];
        float4 yv = y4[i];
        float xs[4] = {xv.x, xv.y, xv.z, xv.w};
        float ys[4] = {yv.x, yv.y, yv.z, yv.w};
#pragma unroll
        for (int c = 0; c < 4; ++c) {
            if (ys[c] > 0.0f) {
                ps += softplusf(-xs[c]);
            } else {
                unsigned k = f2key(xs[c]);
                if (k >= K0) {
                    unsigned p = atomicAdd(&lcount, 1u);       // LDS atomic
                    if (p < LBUF_CAP) lbuf[p] = k;
                    else {  // overflow fallback (mean ~650/block; unreachable)
                        unsigned gi = atomicAdd(&ctrl->cand_count, 1u);
                        if (gi < cap) cand[gi] = k;
                    }
                }
            }
        }
    }
    if (blockIdx.x == 0 && threadIdx.x == 0) {   // tail (n % 4)
        for (int i = n4 << 2; i < n; ++i) {
            float xs = x[i], ys = y[i];
            if (ys > 0.0f) ps += softplusf(-xs);
            else {
                unsigned k = f2key(xs);
                if (k >= K0) {
                    unsigned p = atomicAdd(&lcount, 1u);
                    if (p < LBUF_CAP) lbuf[p] = k;
                    else {
                        unsigned gi = atomicAdd(&ctrl->cand_count, 1u);
                        if (gi < cap) cand[gi] = k;
                    }
                }
            }
        }
    }
    __syncthreads();
    ps = wred(ps);
    if ((threadIdx.x & 63) == 0) atomicAdd(&red, ps);
    const unsigned m = lcount < LBUF_CAP ? lcount : LBUF_CAP;
    if (threadIdx.x == 0) gbase = atomicAdd(&ctrl->cand_count, m);  // ONE per block
    __syncthreads();
    for (unsigned i = threadIdx.x; i < m; i += 256) {
        unsigned gi = gbase + i;
        if (gi < cap) cand[gi] = lbuf[i];
    }
    if (threadIdx.x == 0) atomicAdd(&ctrl->pos_sum, red);
}

// ---------------- stage 1: hist of top-12 bits over candidates --------------
__global__ __launch_bounds__(256)
void k_h1(const unsigned* __restrict__ cand, const float* __restrict__ x,
          const float* __restrict__ y, Ctrl* __restrict__ ctrl, int n) {
    __shared__ unsigned h[NBINS1];
    for (int i = threadIdx.x; i < NBINS1; i += 256) h[i] = 0u;
    __syncthreads();
    const unsigned m = ctrl->cand_count;
    const bool fb = m < ctrl->Kneg;
    const unsigned stride = gridDim.x * blockDim.x;
    for (unsigned i = blockIdx.x * blockDim.x + threadIdx.x; i < m; i += stride)
        atomicAdd(&h[cand[i] >> 20], 1u);
    if (fb) {
        for (unsigned i = blockIdx.x * blockDim.x + threadIdx.x; i < (unsigned)n; i += stride)
            if (y[i] == 0.0f) {
                unsigned k = f2key(x[i]);
                if (k < K0) atomicAdd(&h[k >> 20], 1u);
            }
    }
    __syncthreads();
    const unsigned rot = (blockIdx.x * 997u) & (NBINS1 - 1);
    for (int i = threadIdx.x; i < NBINS1; i += 256) {
        unsigned b = (i + rot) & (NBINS1 - 1);
        if (h[b]) atomicAdd(&ctrl->hist1[b], h[b]);
    }
}

// ---- stage 2: re-derive (b1,r1) in-block; hist of mid-10 bits, top12==b1 ----
__global__ __launch_bounds__(256)
void k_h2(const unsigned* __restrict__ cand, const float* __restrict__ x,
          const float* __restrict__ y, Ctrl* __restrict__ ctrl, int n) {
    __shared__ unsigned h[NBINS2];
    unsigned b1, r1;
    scan_desc(ctrl->hist1, NBINS1, ctrl->Kneg, &b1, &r1);
    for (int i = threadIdx.x; i < NBINS2; i += 256) h[i] = 0u;
    __syncthreads();
    const unsigned m = ctrl->cand_count;
    const bool fb = m < ctrl->Kneg;
    const unsigned stride = gridDim.x * blockDim.x;
    for (unsigned i = blockIdx.x * blockDim.x + threadIdx.x; i < m; i += stride) {
        unsigned k = cand[i];
        if ((k >> 20) == b1) atomicAdd(&h[(k >> 10) & 1023u], 1u);
    }
    if (fb) {
        for (unsigned i = blockIdx.x * blockDim.x + threadIdx.x; i < (unsigned)n; i += stride)
            if (y[i] == 0.0f) {
                unsigned k = f2key(x[i]);
                if (k < K0 && (k >> 20) == b1) atomicAdd(&h[(k >> 10) & 1023u], 1u);
            }
    }
    __syncthreads();
    const unsigned rot = (blockIdx.x * 41u) & (NBINS2 - 1);
    for (int i = threadIdx.x; i < NBINS2; i += 256) {
        unsigned b = (i + rot) & (NBINS2 - 1);
        if (h[b]) atomicAdd(&ctrl->hist2[b], h[b]);
    }
    if (blockIdx.x == 0 && threadIdx.x == 0) { ctrl->b1 = b1; ctrl->r1 = r1; }
}

// ---- stage 3: re-derive (b2,r2); hist of low-10 bits, top22==(b1,b2) -------
__global__ __launch_bounds__(256)
void k_h3(const unsigned* __restrict__ cand, const float* __restrict__ x,
          const float* __restrict__ y, Ctrl* __restrict__ ctrl, int n) {
    __shared__ unsigned h[NBINS2];
    const unsigned b1 = ctrl->b1;
    unsigned b2, r2;
    scan_desc(ctrl->hist2, NBINS2, ctrl->r1, &b2, &r2);
    for (int i = threadIdx.x; i < NBINS2; i += 256) h[i] = 0u;
    __syncthreads();
    const unsigned pre = (b1 << 10) | b2;   // top-22 prefix
    const unsigned m = ctrl->cand_count;
    const bool fb = m < ctrl->Kneg;
    const unsigned stride = gridDim.x * blockDim.x;
    for (unsigned i = blockIdx.x * blockDim.x + threadIdx.x; i < m; i += stride) {
        unsigned k = cand[i];
        if ((k >> 10) == pre) atomicAdd(&h[k & 1023u], 1u);
    }
    if (fb) {
        for (unsigned i = blockIdx.x * blockDim.x + threadIdx.x; i < (unsigned)n; i += stride)
            if (y[i] == 0.0f) {
                unsigned k = f2key(x[i]);
                if (k < K0 && (k >> 10) == pre) atomicAdd(&h[k & 1023u], 1u);
            }
    }
    __syncthreads();
    const unsigned rot = (blockIdx.x * 41u) & (NBINS2 - 1);
    for (int i = threadIdx.x; i < NBINS2; i += 256) {
        unsigned b = (i + rot) & (NBINS2 - 1);
        if (h[b]) atomicAdd(&ctrl->hist3[b], h[b]);
    }
    if (blockIdx.x == 0 && threadIdx.x == 0) { ctrl->b2 = b2; ctrl->r2 = r2; }
}

// ---- final: re-derive (c3,r3) -> exact threshold key H; sum softplus(k>H);
// ---- last block adds r3*softplus(H) + pos_sum and writes the mean ----------
__global__ __launch_bounds__(256)
void k_sum(const unsigned* __restrict__ cand, const float* __restrict__ x,
           const float* __restrict__ y, Ctrl* __restrict__ ctrl,
           const int* __restrict__ pos_num, float* __restrict__ out, int n) {
    __shared__ float red;
    const unsigned b1 = ctrl->b1, b2 = ctrl->b2;
    unsigned c3, r3;
    scan_desc(ctrl->hist3, NBINS2, ctrl->r2, &c3, &r3);
    if (threadIdx.x == 0) red = 0.0f;
    __syncthreads();
    const unsigned H = (b1 << 20) | (b2 << 10) | c3;  // exact k-th largest key
    const unsigned m = ctrl->cand_count;
    const bool fb = m < ctrl->Kneg;
    const unsigned stride = gridDim.x * blockDim.x;
    float s = 0.0f;
    for (unsigned i = blockIdx.x * blockDim.x + threadIdx.x; i < m; i += stride) {
        unsigned k = cand[i];
        if (k > H) s += softplusf(key2f(k));
    }
    if (fb) {
        for (unsigned i = blockIdx.x * blockDim.x + threadIdx.x; i < (unsigned)n; i += stride)
            if (y[i] == 0.0f) {
                unsigned k = f2key(x[i]);
                if (k < K0 && k > H) s += softplusf(key2f(k));
            }
    }
    s = wred(s);
    if ((threadIdx.x & 63) == 0) atomicAdd(&red, s);
    __syncthreads();
    if (threadIdx.x == 0) {
        atomicAdd(&ctrl->neg_sum, red);
        __threadfence();
        unsigned t = atomicAdd(&ctrl->done, 1u);
        if (t == gridDim.x - 1) {                  // last block: all sums landed
            float neg = atomicAdd(&ctrl->neg_sum, 0.0f);   // coherent reads
            float pos = atomicAdd(&ctrl->pos_sum, 0.0f);
            int p = pos_num[0];
            out[0] = (pos + neg + (float)r3 * softplusf(key2f(H))) / (float)(4 * p);
        }
    }
}

extern "C" void kernel_launch(void* const* d_in, const int* in_sizes, int n_in,
                              void* d_out, int out_size, void* d_ws, size_t ws_size,
                              hipStream_t stream) {
    const float* x = (const float*)d_in[0];
    const float* y = (const float*)d_in[1];
    const int* pos_num = (const int*)d_in[2];
    float* out = (float*)d_out;
    const int n = in_sizes[0];

    unsigned* ws = (unsigned*)d_ws;
    Ctrl* ctrl = (Ctrl*)d_ws;
    unsigned* cand = ws + CTRL_BYTES / 4;
    unsigned cap = (ws_size > (size_t)CTRL_BYTES)
                       ? (unsigned)((ws_size - CTRL_BYTES) / 4)
                       : 0u;

    k_init<<<32, 256, 0, stream>>>(ws, pos_num);
    k_main<<<2048, 256, 0, stream>>>(x, y, ctrl, cand, cap, n);
    k_h1<<<256, 256, 0, stream>>>(cand, x, y, ctrl, n);
    k_h2<<<256, 256, 0, stream>>>(cand, x, y, ctrl, n);
    k_h3<<<128, 256, 0, stream>>>(cand, x, y, ctrl, n);
    k_sum<<<256, 256, 0, stream>>>(cand, x, y, ctrl, pos_num, out, n);
}